// Round 6
// baseline (816.467 us; speedup 1.0000x reference)
//
#include <hip/hip_runtime.h>
#include <cstdint>

// out = G @ (x @ W^T + b)      [8192,8192] @ [8192,128]
// mask is ignored: mask == (G==0), so where(mask,0,G) == G identically.
#define NN 8192   // nodes
#define KD 256    // in_dim
#define HD 128    // hidden

// R8: fused kernel, SOFTWARE grid barrier (plain launch).
// R7's cooperative launch never executed (absmax == max|ref| => output
// buffer stayed zeroed; hipLaunchCooperativeKernel failed unchecked,
// likely incompatible with the harness's graph capture). Same fusion,
// launch-mechanism swapped: normal <<<>>> launch + arrival-counter
// barrier in d_ws (zeroed by captured hipMemsetAsync each iteration).
// Deadlock-free by construction: __launch_bounds__(256,4) => VGPR<=128,
// LDS 16 KB => 4 blocks/CU => all 1024 blocks co-resident on 256 CUs.
// Cross-XCD visibility: __threadfence (agent scope) release before
// arrival, acquire after release of the spin (Guideline 16).
// Phases byte-identical to R6 (passed, 523.9 us as 3 dispatches).
#define SPLITK 4
#define KS (NN / SPLITK)   // 2048 k per block
#define BK 128             // k floats per stage
#define NSTEP (KS / BK)    // 16 stages
#define MROWS 32           // G rows per block
#define NBLK 1024

typedef __attribute__((ext_vector_type(4))) float   f32x4;
typedef __attribute__((ext_vector_type(8))) __bf16  bf16x8;
typedef __attribute__((ext_vector_type(8))) unsigned short ushort8;

// fp32 -> bf16 round-to-nearest-even
static __device__ __forceinline__ unsigned short f2bf(float f) {
  unsigned u = __builtin_bit_cast(unsigned, f);
  u += 0x7FFFu + ((u >> 16) & 1u);
  return (unsigned short)(u >> 16);
}

static __device__ __forceinline__ bf16x8 pack8(const float4 a, const float4 b) {
  ushort8 u;
  u[0] = f2bf(a.x); u[1] = f2bf(a.y); u[2] = f2bf(a.z); u[3] = f2bf(a.w);
  u[4] = f2bf(b.x); u[5] = f2bf(b.y); u[6] = f2bf(b.z); u[7] = f2bf(b.w);
  return __builtin_bit_cast(bf16x8, u);
}

#define MFMA(a, b, c) __builtin_amdgcn_mfma_f32_16x16x32_bf16((a), (b), (c), 0, 0, 0)

// software grid barrier: counter pre-zeroed host-side (captured memset).
static __device__ __forceinline__ void gbar(unsigned* cnt) {
  __syncthreads();                 // all waves of this block done with phase
  if (threadIdx.x == 0) {
    __threadfence();               // release: this block's stores -> coherent point
    __hip_atomic_fetch_add(cnt, 1u, __ATOMIC_RELAXED, __HIP_MEMORY_SCOPE_AGENT);
    while (__hip_atomic_load(cnt, __ATOMIC_RELAXED, __HIP_MEMORY_SCOPE_AGENT) < NBLK)
      __builtin_amdgcn_s_sleep(16);
  }
  __syncthreads();                 // whole block waits on the spinner
  __threadfence();                 // acquire (all threads): drop stale cache lines
}

// ---------------------------------------------------------------------------
// Fused kernel: 1024 blocks x 256 threads, 4 blocks/CU.
// fc -> barrier -> spmm (R6) -> barrier -> reduce.
// ---------------------------------------------------------------------------
__global__ __launch_bounds__(256, 4) void fused_kernel(
    const float* __restrict__ x, const float* __restrict__ G,
    const float* __restrict__ W, const float* __restrict__ bias,
    unsigned short* __restrict__ ht, float* __restrict__ P,
    float* __restrict__ out, unsigned* __restrict__ bar)
{
  __shared__ __align__(16) unsigned short gsh[2][MROWS * BK];   // 2 x 8 KB

  const int tid  = threadIdx.x;
  const int lane = tid & 63;
  const int wave = tid >> 6;
  const int l15  = lane & 15;
  const int lq   = lane >> 4;

  // ---------------- Phase 1: fc  (blocks 0..127, 512 wave-tasks) ----------
  if (blockIdx.x < 128) {
    const int m0 = blockIdx.x * 64 + wave * 16;

    f32x4 acc[8];
#pragma unroll
    for (int t = 0; t < 8; ++t) acc[t] = (f32x4)0.0f;

    const float* xr = x + (size_t)(m0 + l15) * KD;
#pragma unroll 1
    for (int s = 0; s < KD / 32; ++s) {
      const int k = s * 32 + lq * 8;
      const bf16x8 af = pack8(*(const float4*)(xr + k), *(const float4*)(xr + k + 4));
#pragma unroll
      for (int t = 0; t < 8; ++t) {
        const float* wr = W + (size_t)(t * 16 + l15) * KD + k;
        const bf16x8 bfr = pack8(*(const float4*)wr, *(const float4*)(wr + 4));
        acc[t] = MFMA(af, bfr, acc[t]);
      }
    }

    // C/D layout: col = lane&15, row = (lane>>4)*4 + reg.
#pragma unroll
    for (int t = 0; t < 8; ++t) {
      const int n  = t * 16 + l15;
      const float bv = bias[n];
      const int mr = m0 + lq * 4;
      uint2 v;
      v.x = (unsigned)f2bf(acc[t][0] + bv) | ((unsigned)f2bf(acc[t][1] + bv) << 16);
      v.y = (unsigned)f2bf(acc[t][2] + bv) | ((unsigned)f2bf(acc[t][3] + bv) << 16);
      *(uint2*)(ht + (size_t)n * NN + mr) = v;
    }
  }

  gbar(&bar[0]);   // ht visible device-wide

  // ---------------- Phase 2: spmm (identical to R6) ------------------------
  {
    const int mtile = blockIdx.x >> 2;
    const int ks    = blockIdx.x & 3;
    const int m0    = mtile * MROWS;
    const int kb0   = ks * KS;

    const int sr = tid >> 3;
    const int sc = tid & 7;
    const float4* gsrc = (const float4*)(G + (size_t)(m0 + sr) * NN + kb0) + sc * 4;
    const int wofs0 = sr * BK + (((sc * 2 + 0) ^ (sr & 7)) * 8);
    const int wofs1 = sr * BK + (((sc * 2 + 1) ^ (sr & 7)) * 8);

    const int asw = l15 & 7;
    const unsigned short* hrow = ht + (size_t)(wave * 32 + l15) * NN + kb0 + lq * 8;

    f32x4 acc[2][2];
    acc[0][0] = (f32x4)0.0f; acc[0][1] = (f32x4)0.0f;
    acc[1][0] = (f32x4)0.0f; acc[1][1] = (f32x4)0.0f;

    {
      const float4 a = gsrc[0], b2 = gsrc[1], c = gsrc[2], d = gsrc[3];
      *(bf16x8*)&gsh[0][wofs0] = pack8(a, b2);
      *(bf16x8*)&gsh[0][wofs1] = pack8(c, d);
    }
    __syncthreads();

#pragma unroll 1
    for (int s = 0; s < NSTEP; ++s) {
      const int b = s & 1;

      // hb first (vmcnt wait for MFMA = these 8, G prefetch stays in flight)
      uint4 hb[4][2];
#pragma unroll
      for (int ksub = 0; ksub < 4; ++ksub)
#pragma unroll
        for (int t = 0; t < 2; ++t)
          hb[ksub][t] =
              *(const uint4*)(hrow + (size_t)t * 16 * NN + s * BK + ksub * 32);

      float4 n0, n1, n2, n3;
      if (s + 1 < NSTEP) {
        const float4* p = gsrc + (s + 1) * (BK / 4);
        n0 = p[0]; n1 = p[1]; n2 = p[2]; n3 = p[3];
      }

#pragma unroll
      for (int ksub = 0; ksub < 4; ++ksub) {
        const int co = (((ksub * 4 + lq) ^ asw)) * 8;
        const bf16x8 af0 = *(const bf16x8*)&gsh[b][l15 * BK + co];
        const bf16x8 af1 = *(const bf16x8*)&gsh[b][(16 + l15) * BK + co];
        acc[0][0] = MFMA(af0, __builtin_bit_cast(bf16x8, hb[ksub][0]), acc[0][0]);
        acc[0][1] = MFMA(af0, __builtin_bit_cast(bf16x8, hb[ksub][1]), acc[0][1]);
        acc[1][0] = MFMA(af1, __builtin_bit_cast(bf16x8, hb[ksub][0]), acc[1][0]);
        acc[1][1] = MFMA(af1, __builtin_bit_cast(bf16x8, hb[ksub][1]), acc[1][1]);
      }

      __syncthreads();
      if (s + 1 < NSTEP) {
        *(bf16x8*)&gsh[b ^ 1][wofs0] = pack8(n0, n1);
        *(bf16x8*)&gsh[b ^ 1][wofs1] = pack8(n2, n3);
      }
      __syncthreads();
    }

    // split-K partials, P[ks][m][n]. C/D: col=lane&15, row=lq*4+reg.
    float* __restrict__ pp = P + (size_t)ks * NN * HD;
#pragma unroll
    for (int a = 0; a < 2; ++a)
#pragma unroll
      for (int t = 0; t < 2; ++t) {
        const int n  = wave * 32 + t * 16 + l15;
        const int mr = m0 + a * 16 + lq * 4;
#pragma unroll
        for (int r = 0; r < 4; ++r)
          pp[(size_t)(mr + r) * HD + n] = acc[a][t][r];
      }
  }

  gbar(&bar[16]);   // P visible device-wide

  // ---------------- Phase 3: reduce (1 float4 per thread) ------------------
  {
    const f32x4* Pv = (const f32x4*)P;
    const int idx = blockIdx.x * 256 + tid;   // 0..262143
    const int S = NN * HD / 4;
    f32x4 s = Pv[idx];
#pragma unroll
    for (int k = 1; k < SPLITK; ++k) s += Pv[(size_t)k * S + idx];
    ((f32x4*)out)[idx] = s;
  }
}

extern "C" void kernel_launch(void* const* d_in, const int* in_sizes, int n_in,
                              void* d_out, int out_size, void* d_ws, size_t ws_size,
                              hipStream_t stream) {
  const float* x = (const float*)d_in[0];
  const float* G = (const float*)d_in[1];
  // d_in[2] = mask: NEVER read. mask == (G==0) => where(mask,0,G) == G.
  const float* W = (const float*)d_in[3];
  const float* b = (const float*)d_in[4];
  float* out = (float*)d_out;

  unsigned short* ht = (unsigned short*)d_ws;                  // 2 MB
  unsigned* bar = (unsigned*)((char*)d_ws + (2u << 20));       // 128 B counters
  float* P = (float*)((char*)d_ws + (4u << 20));               // 16 MB partials

  // zero barrier counters (workspace is re-poisoned every iteration);
  // async + in-stream => graph-capture-safe and ordered before the kernel.
  hipMemsetAsync(bar, 0, 128, stream);
  fused_kernel<<<NBLK, 256, 0, stream>>>(x, G, W, b, ht, P, out, bar);
}

// Round 7
// 538.857 us; speedup vs baseline: 1.5152x; 1.5152x over previous
//
#include <hip/hip_runtime.h>
#include <cstdint>

// out = G @ (x @ W^T + b)      [8192,8192] @ [8192,128]
// mask is ignored: mask == (G==0), so where(mask,0,G) == G identically.
#define NN 8192   // nodes
#define KD 256    // in_dim
#define HD 128    // hidden

// R9: split kernels (fusion bought nothing; R8's fence storm reverted).
// R8's counters: FETCH 151 MB (<G's 256 MB -> L3 serves ~40%), hbm 4.7%,
// VALU 2%, Mfma 1.5% -> STALL-bound, not BW-bound. Two fixes:
// (1) ht traffic: MROWS 32->128, SPLITK 4->8 => 512 blocks, ht re-read
//     512->128 MB; ks==bid&7 aligns with round-robin XCD placement so each
//     XCD's L2 holds ONE 256 KB ht slab -> ht reads become L2 hits.
// (2) G pipeline: __syncthreads emits s_waitcnt vmcnt(0) (drains prefetch
//     every stage -> R6's null). Raw s_barrier + depth-2 register prefetch:
//     compiler's data-dep wait at the ds_write is vmcnt(4), leaving stage
//     s+2's loads in flight across both barriers (T3/T4 in plain HIP).
#define SPLITK 8
#define KS (NN / SPLITK)   // 1024 k per block
#define BK 64              // k floats per stage
#define NSTEP (KS / BK)    // 16 stages
#define MROWS 128          // G rows per block

typedef __attribute__((ext_vector_type(4))) float   f32x4;
typedef __attribute__((ext_vector_type(8))) __bf16  bf16x8;
typedef __attribute__((ext_vector_type(8))) unsigned short ushort8;

// fp32 -> bf16 round-to-nearest-even
static __device__ __forceinline__ unsigned short f2bf(float f) {
  unsigned u = __builtin_bit_cast(unsigned, f);
  u += 0x7FFFu + ((u >> 16) & 1u);
  return (unsigned short)(u >> 16);
}

static __device__ __forceinline__ bf16x8 pack8(const float4 a, const float4 b) {
  ushort8 u;
  u[0] = f2bf(a.x); u[1] = f2bf(a.y); u[2] = f2bf(a.z); u[3] = f2bf(a.w);
  u[4] = f2bf(b.x); u[5] = f2bf(b.y); u[6] = f2bf(b.z); u[7] = f2bf(b.w);
  return __builtin_bit_cast(bf16x8, u);
}

#define MFMA(a, b, c) __builtin_amdgcn_mfma_f32_16x16x32_bf16((a), (b), (c), 0, 0, 0)

// ---------------------------------------------------------------------------
// Kernel A: ht[n][m] = sum_k x[m][k]*W[n][k] + b[n], bf16, [HD][NN].
// (unchanged from the 521 us baseline)
// ---------------------------------------------------------------------------
__global__ __launch_bounds__(64) void fc_ht_kernel(
    const float* __restrict__ x, const float* __restrict__ W,
    const float* __restrict__ bias, unsigned short* __restrict__ ht)
{
  const int lane = threadIdx.x & 63;
  const int l15  = lane & 15;
  const int lq   = lane >> 4;
  const int m0   = blockIdx.x * 16;

  f32x4 acc[8];
#pragma unroll
  for (int t = 0; t < 8; ++t) acc[t] = (f32x4)0.0f;

  const float* xr = x + (size_t)(m0 + l15) * KD;
#pragma unroll 1
  for (int s = 0; s < KD / 32; ++s) {
    const int k = s * 32 + lq * 8;
    const bf16x8 af = pack8(*(const float4*)(xr + k), *(const float4*)(xr + k + 4));
#pragma unroll
    for (int t = 0; t < 8; ++t) {
      const float* wr = W + (size_t)(t * 16 + l15) * KD + k;
      const bf16x8 bfr = pack8(*(const float4*)wr, *(const float4*)(wr + 4));
      acc[t] = MFMA(af, bfr, acc[t]);
    }
  }

  // C/D layout: col = lane&15, row = (lane>>4)*4 + reg.
#pragma unroll
  for (int t = 0; t < 8; ++t) {
    const int n  = t * 16 + l15;
    const float bv = bias[n];
    const int mr = m0 + lq * 4;
    uint2 v;
    v.x = (unsigned)f2bf(acc[t][0] + bv) | ((unsigned)f2bf(acc[t][1] + bv) << 16);
    v.y = (unsigned)f2bf(acc[t][2] + bv) | ((unsigned)f2bf(acc[t][3] + bv) << 16);
    *(uint2*)(ht + (size_t)n * NN + mr) = v;
  }
}

// ---------------------------------------------------------------------------
// Kernel B: spmm. 512 blocks x 512 threads (8 waves = 2m x 4n), 2 blocks/CU.
// Per block: 128 G rows x 1024 k. Per stage (BK=64): G 32 KB fp32 reg-read
// (64 B contiguous/thread), packed bf16 -> 16 KB LDS; ht 4x uint4/wave from
// the XCD-local L2 slab; 16 MFMA/wave. Depth-2 G prefetch in registers.
// ---------------------------------------------------------------------------
__global__ __launch_bounds__(512, 2) void spmm_kernel(
    const float* __restrict__ G, const unsigned short* __restrict__ ht,
    float* __restrict__ P)
{
  __shared__ __align__(16) unsigned short gsh[2][MROWS * BK];   // 2 x 16 KB

  const int tid   = threadIdx.x;
  const int lane  = tid & 63;
  const int wave  = tid >> 6;          // 0..7
  const int l15   = lane & 15;
  const int lq    = lane >> 4;
  const int wm    = wave >> 2;         // 0..1 (64-row half)
  const int wn    = wave & 3;          // 0..3 (32-col quarter)
  const int mtile = blockIdx.x >> 3;   // 0..63
  const int ks    = blockIdx.x & 7;    // == XCD under round-robin placement
  const int m0    = mtile * MROWS;
  const int kb0   = ks * KS;

  // staging map: row r = tid>>2 (0..127), q = tid&3 -> 16 floats (64 B)
  const int r = tid >> 2;
  const int q = tid & 3;
  const float4* gsrc4 = (const float4*)(G + (size_t)(m0 + r) * NN + kb0) + q * 4;
  const int wofs0 = r * BK + (((2 * q + 0) ^ (r & 7)) * 8);   // ushort offsets
  const int wofs1 = r * BK + (((2 * q + 1) ^ (r & 7)) * 8);

  const unsigned short* hrow = ht + (size_t)(wn * 32 + l15) * NN + kb0 + lq * 8;

  f32x4 acc[4][2];
#pragma unroll
  for (int mf = 0; mf < 4; ++mf)
#pragma unroll
    for (int nf = 0; nf < 2; ++nf) acc[mf][nf] = (f32x4)0.0f;

  float4 gA[4], gB[4];

  // prologue: issue G(0)->gA and G(1)->gB; write stage 0; barrier.
#pragma unroll
  for (int j = 0; j < 4; ++j) gA[j] = gsrc4[j];
#pragma unroll
  for (int j = 0; j < 4; ++j) gB[j] = gsrc4[16 + j];
  *(bf16x8*)&gsh[0][wofs0] = pack8(gA[0], gA[1]);   // auto vmcnt leaves gB in flight
  *(bf16x8*)&gsh[0][wofs1] = pack8(gA[2], gA[3]);
  __builtin_amdgcn_s_barrier();

  // STEP: hb(s) + G(s+2)->GLD, compute from gsh[CB], barrier,
  //       write GWR (=G(s+1), waits vmcnt(4): GLD stays in flight), barrier.
#define STEP(s_, GLD_, GWR_, CB_, NB_)                                         \
  do {                                                                         \
    uint4 hb[2][2];                                                            \
    _Pragma("unroll")                                                          \
    for (int ksub = 0; ksub < 2; ++ksub)                                       \
      _Pragma("unroll")                                                        \
      for (int nf = 0; nf < 2; ++nf)                                           \
        hb[ksub][nf] = *(const uint4*)(hrow + (size_t)nf * 16 * NN +           \
                                       (s_) * BK + ksub * 32);                 \
    if ((s_) + 2 < NSTEP) {                                                    \
      _Pragma("unroll")                                                        \
      for (int j = 0; j < 4; ++j) GLD_[j] = gsrc4[((s_) + 2) * 16 + j];        \
    }                                                                          \
    _Pragma("unroll")                                                          \
    for (int ksub = 0; ksub < 2; ++ksub) {                                     \
      bf16x8 af[4];                                                            \
      _Pragma("unroll")                                                        \
      for (int mf = 0; mf < 4; ++mf) {                                         \
        const int row = wm * 64 + mf * 16 + l15;                               \
        const int ch  = (ksub * 4 + lq) ^ (row & 7);                           \
        af[mf] = *(const bf16x8*)&gsh[CB_][row * BK + ch * 8];                 \
      }                                                                        \
      _Pragma("unroll")                                                        \
      for (int mf = 0; mf < 4; ++mf)                                           \
        _Pragma("unroll")                                                      \
        for (int nf = 0; nf < 2; ++nf)                                         \
          acc[mf][nf] = MFMA(af[mf], __builtin_bit_cast(bf16x8, hb[ksub][nf]), \
                             acc[mf][nf]);                                     \
    }                                                                          \
    __builtin_amdgcn_sched_barrier(0);   /* pin MFMA cluster before barrier */ \
    __builtin_amdgcn_s_barrier();        /* all reads of gsh[CB_] done */      \
    if ((s_) + 1 < NSTEP) {                                                    \
      *(bf16x8*)&gsh[NB_][wofs0] = pack8(GWR_[0], GWR_[1]);                    \
      *(bf16x8*)&gsh[NB_][wofs1] = pack8(GWR_[2], GWR_[3]);                    \
    }                                                                          \
    __builtin_amdgcn_s_barrier();        /* gsh[NB_] ready */                  \
  } while (0)

#pragma unroll 1
  for (int s = 0; s < NSTEP; s += 2) {
    STEP(s,     gA, gB, 0, 1);   // even: load s+2 -> gA, write G(s+1) from gB
    STEP(s + 1, gB, gA, 1, 0);   // odd : load s+3 -> gB, write G(s+2) from gA
  }

  // epilogue: split-K partials, P[ks][m][n]. C/D: col=lane&15, row=lq*4+reg.
  float* __restrict__ pp = P + (size_t)ks * NN * HD;
#pragma unroll
  for (int mf = 0; mf < 4; ++mf)
#pragma unroll
    for (int nf = 0; nf < 2; ++nf) {
      const int n  = wn * 32 + nf * 16 + l15;
      const int mr = m0 + wm * 64 + mf * 16 + lq * 4;
#pragma unroll
      for (int rr = 0; rr < 4; ++rr)
        pp[(size_t)(mr + rr) * HD + n] = acc[mf][nf][rr];
    }
}

// ---------------------------------------------------------------------------
// Kernel C: out[m][n] = sum_ks P[ks][m][n].
// ---------------------------------------------------------------------------
__global__ __launch_bounds__(256) void reduce_kernel(
    const f32x4* __restrict__ P, f32x4* __restrict__ out)
{
  const int idx = blockIdx.x * 256 + threadIdx.x;   // 0..262143 float4s
  const int S = NN * HD / 4;
  f32x4 s = P[idx];
#pragma unroll
  for (int k = 1; k < SPLITK; ++k) s += P[(size_t)k * S + idx];
  out[idx] = s;
}

extern "C" void kernel_launch(void* const* d_in, const int* in_sizes, int n_in,
                              void* d_out, int out_size, void* d_ws, size_t ws_size,
                              hipStream_t stream) {
  const float* x = (const float*)d_in[0];
  const float* G = (const float*)d_in[1];
  // d_in[2] = mask: NEVER read. mask == (G==0) => where(mask,0,G) == G.
  const float* W = (const float*)d_in[3];
  const float* b = (const float*)d_in[4];
  float* out = (float*)d_out;

  unsigned short* ht = (unsigned short*)d_ws;                  // 2 MB
  float* P = (float*)((char*)d_ws + (4u << 20));               // 32 MB partials

  fc_ht_kernel<<<NN / 16, 64, 0, stream>>>(x, W, b, ht);
  spmm_kernel<<<(NN / MROWS) * SPLITK, 512, 0, stream>>>(G, ht, P);
  reduce_kernel<<<NN * HD / 4 / 256, 256, 0, stream>>>((const f32x4*)P, (f32x4*)out);
}